// Round 2
// baseline (873.084 us; speedup 1.0000x reference)
//
#include <hip/hip_runtime.h>

typedef unsigned short u16;
typedef unsigned int u32;
typedef __attribute__((ext_vector_type(8))) __bf16 bf16x8;
typedef __attribute__((ext_vector_type(4))) float f32x4;
typedef __attribute__((ext_vector_type(8))) u16 u16x8;

// ---------- helpers ----------

__device__ __forceinline__ u16 f2bf(float f) {
    union { float f; u32 u; } v; v.f = f;
    u32 r = v.u + 0x7FFFu + ((v.u >> 16) & 1u);   // RNE
    return (u16)(r >> 16);
}

__device__ __forceinline__ void gload16(const void* g, void* l) {
    __builtin_amdgcn_global_load_lds(
        (const __attribute__((address_space(1))) u32*)g,
        (__attribute__((address_space(3))) u32*)l,
        16, 0, 0);
}

// ---------- fp32 -> bf16 elementwise (8 elems/thread) ----------
__global__ __launch_bounds__(256) void conv_bf16(
    const float* __restrict__ in, u16* __restrict__ out) {
    const size_t i = (size_t)blockIdx.x * 256 + threadIdx.x;
    const float4 a = ((const float4*)in)[i * 2];
    const float4 b = ((const float4*)in)[i * 2 + 1];
    u16x8 o;
    o[0] = f2bf(a.x); o[1] = f2bf(a.y); o[2] = f2bf(a.z); o[3] = f2bf(a.w);
    o[4] = f2bf(b.x); o[5] = f2bf(b.y); o[6] = f2bf(b.z); o[7] = f2bf(b.w);
    ((u16x8*)out)[i] = o;
}

// ---------- Ub[m,k] = bf16(U[m,k] * relu(S[k]+delta[k])) ----------
__global__ __launch_bounds__(64) void conv_scale(
    const float* __restrict__ U, const float* __restrict__ S,
    const float* __restrict__ D, u16* __restrict__ out) {
    const int m = blockIdx.y;
    const int k = (blockIdx.x * 64 + threadIdx.x) * 8;
    const size_t base = (size_t)m * 3072 + k;
    const float4 a = *(const float4*)&U[base];
    const float4 b = *(const float4*)&U[base + 4];
    const float4 s1 = *(const float4*)&S[k], s2 = *(const float4*)&S[k + 4];
    const float4 d1 = *(const float4*)&D[k], d2 = *(const float4*)&D[k + 4];
    u16x8 o;
    o[0] = f2bf(a.x * fmaxf(s1.x + d1.x, 0.f));
    o[1] = f2bf(a.y * fmaxf(s1.y + d1.y, 0.f));
    o[2] = f2bf(a.z * fmaxf(s1.z + d1.z, 0.f));
    o[3] = f2bf(a.w * fmaxf(s1.w + d1.w, 0.f));
    o[4] = f2bf(b.x * fmaxf(s2.x + d2.x, 0.f));
    o[5] = f2bf(b.y * fmaxf(s2.y + d2.y, 0.f));
    o[6] = f2bf(b.z * fmaxf(s2.z + d2.z, 0.f));
    o[7] = f2bf(b.w * fmaxf(s2.w + d2.w, 0.f));
    *(u16x8*)&out[base] = o;
}

// ---------- V^T -> bf16 (tiled transpose + convert) ----------
__global__ __launch_bounds__(256) void transpose_conv(
    const float* __restrict__ V, u16* __restrict__ Vt, int n) {
    __shared__ float tile[64][65];
    const int k0 = blockIdx.y * 64, j0 = blockIdx.x * 64;
    const int t = threadIdx.x;
    const int r = t >> 4, c4 = t & 15;
#pragma unroll
    for (int i = 0; i < 4; i++) {
        int row = i * 16 + r;
        const float4 v = *(const float4*)&V[(size_t)(k0 + row) * n + j0 + c4 * 4];
        tile[row][c4 * 4 + 0] = v.x;
        tile[row][c4 * 4 + 1] = v.y;
        tile[row][c4 * 4 + 2] = v.z;
        tile[row][c4 * 4 + 3] = v.w;
    }
    __syncthreads();
#pragma unroll
    for (int i = 0; i < 4; i++) {
        int row = i * 16 + r;  // local j
        ushort4 o;
        o.x = f2bf(tile[c4 * 4 + 0][row]);
        o.y = f2bf(tile[c4 * 4 + 1][row]);
        o.z = f2bf(tile[c4 * 4 + 2][row]);
        o.w = f2bf(tile[c4 * 4 + 3][row]);
        *(ushort4*)&Vt[(size_t)(j0 + row) * n + k0 + c4 * 4] = o;
    }
}

// ---------- bf16 NT GEMM, 256x256 tile, 4-phase/K-tile counted-vmcnt schedule ----------
// 512 threads = 8 waves (2M x 4N); each wave owns 128x64 output (8x4 16x16x32 frags).
// LDS per operand: [2 dbuf][256 rows][64 cols] bf16 (32 KiB tiles, 128 KiB total).
// st_16x32 XOR swizzle (m201-verified near-zero bank conflict for this read pattern):
// 16B chunk bit1 ^= row bit2, applied on the pre-swizzled GLOBAL source address
// (global_load_lds dest must stay lane-linear) and de-applied at the fragment read.
// Stage granularity: row-quarter (64 rows x 64 cols = 8KB = one gload16 x 512 thr).
// Quarter last-LDS-read: A q0/q2 + all B quarters at phase 3; A q1/q3 at phase 4.
// Issue plan per K-tile tt: ph1 -> A q1,q3 (tt+1); ph2 -> B q2,q3 (tt+1);
// ph4 -> A q0,q2 + B q0,q1 (tt+2); one boundary s_waitcnt vmcnt(4) per K-tile
// (never 0 in steady state; the 4 newest loads stay in flight across the barrier).
// Requires M%256==0, N%256==0, K%64==0, K>=128, grid%8==0.
__global__ __launch_bounds__(512, 2) void gemm256(
    const u16* __restrict__ A, const u16* __restrict__ B,
    float* __restrict__ C, int M, int N, int K) {
    __shared__ u16 As[2][16384];
    __shared__ u16 Bs[2][16384];
    const int t = threadIdx.x;

    // XCD-aware swizzle (bijective since grid size % 8 == 0)
    const int nbx = gridDim.x;
    const int bid = blockIdx.y * nbx + blockIdx.x;
    const int cpx = (nbx * gridDim.y) >> 3;
    const int sid = (bid & 7) * cpx + (bid >> 3);
    const int m0 = (sid / nbx) * 256, n0 = (sid % nbx) * 256;

    const int lane = t & 63, quad = lane >> 4, lrow = lane & 15;
    const int wave = t >> 6, wr = wave >> 2, wc = wave & 3;

    // staging: thread t covers row (t>>3), pre-swizzled 16B chunk of one 64x64 quarter
    const int schunk = (t & 7) ^ ((t >> 4) & 2);   // chunk bit1 ^= row bit2 (t bit5)
    const u16* Ag = A + (size_t)(m0 + (t >> 3)) * K + schunk * 8;
    const u16* Bg = B + (size_t)(n0 + (t >> 3)) * K + schunk * 8;

    // fragment read offsets (u16 index inside one [256][64] region), read-side swizzle
    const int swzq = quad ^ ((lrow >> 1) & 2);     // quad bit1 ^= row bit2
    const int aoff = (wr * 128 + lrow) * 64 + swzq * 8;
    const int boff = (wc * 64 + lrow) * 64 + swzq * 8;

    f32x4 acc[8][4] = {};

    // stage one quarter (q=0..3: rows q*64..q*64+63) of K-tile starting at u16 col kbe
#define STGA(dst, q, kbe) gload16(Ag + (size_t)(q) * 64 * K + (kbe), (char*)(dst) + (q) * 8192 + t * 16)
#define STGB(dst, q, kbe) gload16(Bg + (size_t)(q) * 64 * K + (kbe), (char*)(dst) + (q) * 8192 + t * 16)

    const int NT = K >> 6;
    // prologue: tile0 all 8 quarters; tile1's ph4-equivalent quad
    STGA(As[0], 0, 0); STGA(As[0], 1, 0); STGA(As[0], 2, 0); STGA(As[0], 3, 0);
    STGB(Bs[0], 0, 0); STGB(Bs[0], 1, 0); STGB(Bs[0], 2, 0); STGB(Bs[0], 3, 0);
    if (NT > 1) {
        STGA(As[1], 0, 64); STGA(As[1], 2, 64);
        STGB(Bs[1], 0, 64); STGB(Bs[1], 1, 64);
        asm volatile("s_waitcnt vmcnt(4)" ::: "memory");
    } else {
        asm volatile("s_waitcnt vmcnt(0)" ::: "memory");
    }
    __builtin_amdgcn_s_barrier();

    for (int tt = 0; tt < NT; ++tt) {
        const int b = tt & 1;
        const u16* Acur = As[b];
        const u16* Bcur = Bs[b];
        u16* Anxt = As[b ^ 1];
        u16* Bnxt = Bs[b ^ 1];
        bf16x8 bq[4], aq[4];

#define PHASE_TAIL(OFF)                                                       \
        __builtin_amdgcn_s_barrier();                                         \
        asm volatile("s_waitcnt lgkmcnt(0)" ::: "memory");                    \
        __builtin_amdgcn_sched_barrier(0);                                    \
        __builtin_amdgcn_s_setprio(1);                                        \
        _Pragma("unroll")                                                     \
        for (int mi = 0; mi < 4; mi++)                                        \
            _Pragma("unroll")                                                 \
            for (int ni = 0; ni < 4; ni++)                                    \
                acc[mi + OFF][ni] = __builtin_amdgcn_mfma_f32_16x16x32_bf16(  \
                    aq[mi], bq[ni], acc[mi + OFF][ni], 0, 0, 0);              \
        __builtin_amdgcn_s_setprio(0);

        // ---- phase 1: kk=0, mi 0-3 (8 ds_read) | stage A q1,q3 (tt+1) ----
#pragma unroll
        for (int ni = 0; ni < 4; ni++) bq[ni] = *(const bf16x8*)&Bcur[boff + ni * 1024];
#pragma unroll
        for (int mi = 0; mi < 4; mi++) aq[mi] = *(const bf16x8*)&Acur[aoff + mi * 1024];
        if (tt + 1 < NT) { STGA(Anxt, 1, (tt + 1) * 64); STGA(Anxt, 3, (tt + 1) * 64); }
        PHASE_TAIL(0)
        __builtin_amdgcn_s_barrier();

        // ---- phase 2: kk=0, mi 4-7 (4 ds_read) | stage B q2,q3 (tt+1) ----
#pragma unroll
        for (int mi = 0; mi < 4; mi++) aq[mi] = *(const bf16x8*)&Acur[aoff + (mi + 4) * 1024];
        if (tt + 1 < NT) { STGB(Bnxt, 2, (tt + 1) * 64); STGB(Bnxt, 3, (tt + 1) * 64); }
        PHASE_TAIL(4)
        __builtin_amdgcn_s_barrier();

        // ---- phase 3: kk=1, mi 0-3 (8 ds_read) | no stage ----
#pragma unroll
        for (int ni = 0; ni < 4; ni++) bq[ni] = *(const bf16x8*)&Bcur[boff + ni * 1024 + 32];
#pragma unroll
        for (int mi = 0; mi < 4; mi++) aq[mi] = *(const bf16x8*)&Acur[aoff + mi * 1024 + 32];
        PHASE_TAIL(0)
        __builtin_amdgcn_s_barrier();

        // ---- phase 4: kk=1, mi 4-7 (4 ds_read) | stage A q0,q2 + B q0,q1 (tt+2) ----
#pragma unroll
        for (int mi = 0; mi < 4; mi++) aq[mi] = *(const bf16x8*)&Acur[aoff + (mi + 4) * 1024 + 32];
        if (tt + 2 < NT) {
            STGA((u16*)Acur, 0, (tt + 2) * 64); STGA((u16*)Acur, 2, (tt + 2) * 64);
            STGB((u16*)Bcur, 0, (tt + 2) * 64); STGB((u16*)Bcur, 1, (tt + 2) * 64);
        }
        PHASE_TAIL(4)
        if (tt + 2 < NT)
            asm volatile("s_waitcnt vmcnt(4)" ::: "memory");  // tt+1 fully landed; 4 newest stay in flight
        else
            asm volatile("s_waitcnt vmcnt(0)" ::: "memory");  // tail drain
        __builtin_amdgcn_s_barrier();
#undef PHASE_TAIL
    }
#undef STGA
#undef STGB

    // epilogue: C/D layout col=lane&15, row=quad*4+reg
#pragma unroll
    for (int mi = 0; mi < 8; mi++) {
#pragma unroll
        for (int rr = 0; rr < 4; rr++) {
            const int row = m0 + wr * 128 + mi * 16 + quad * 4 + rr;
            float* cp = C + (size_t)row * N + n0 + wc * 64 + lrow;
#pragma unroll
            for (int ni = 0; ni < 4; ni++) cp[ni * 16] = acc[mi][ni][rr];
        }
    }
}

// ---------- Kron apply: WtT[o,:] = bf16( (Q1 (x) Q2 (x) Q3) @ W[o,:] ) ----------
__global__ __launch_bounds__(256) void kron_apply(
    const float* __restrict__ W, const float* __restrict__ Q1,
    const float* __restrict__ Q2, const float* __restrict__ Q3,
    u16* __restrict__ WtT) {
    __shared__ float T0[3072], T1[3072];
    __shared__ float Q1s[256], Q2s[256], Q3s[144];
    const int o = blockIdx.x, t = threadIdx.x;
#pragma unroll
    for (int i = 0; i < 12; i++) T0[t + i * 256] = W[(size_t)o * 3072 + t + i * 256];
    Q1s[t] = Q1[t];
    Q2s[t] = Q2[t];
    if (t < 144) Q3s[t] = Q3[t];
    __syncthreads();
#pragma unroll
    for (int i = 0; i < 12; i++) {
        int e = t + i * 256;
        int d1 = e / 192, rem = e % 192;
        float s = 0.f;
#pragma unroll
        for (int j1 = 0; j1 < 16; j1++) s += Q1s[d1 * 16 + j1] * T0[j1 * 192 + rem];
        T1[e] = s;
    }
    __syncthreads();
#pragma unroll
    for (int i = 0; i < 12; i++) {
        int e = t + i * 256;
        int j3 = e % 12, d2 = (e / 12) & 15, d1 = e / 192;
        float s = 0.f;
#pragma unroll
        for (int j2 = 0; j2 < 16; j2++) s += Q2s[d2 * 16 + j2] * T1[d1 * 192 + j2 * 12 + j3];
        T0[e] = s;
    }
    __syncthreads();
#pragma unroll
    for (int i = 0; i < 12; i++) {
        int e = t + i * 256;
        int d3 = e % 12, b = e - d3;
        float s = 0.f;
#pragma unroll
        for (int j3 = 0; j3 < 12; j3++) s += Q3s[d3 * 12 + j3] * T0[b + j3];
        WtT[(size_t)o * 3072 + e] = f2bf(s);
    }
}

// ---------- launch ----------
extern "C" void kernel_launch(void* const* d_in, const int* in_sizes, int n_in,
                              void* d_out, int out_size, void* d_ws, size_t ws_size,
                              hipStream_t stream) {
    const float* x   = (const float*)d_in[0];  // [4,4096,3072]
    const float* U   = (const float*)d_in[1];  // [3072,3072]
    const float* S   = (const float*)d_in[2];  // [3072]
    const float* V   = (const float*)d_in[3];  // [3072,3072]
    const float* dl  = (const float*)d_in[4];  // [3072]
    const float* Q1  = (const float*)d_in[5];  // [16,16]
    const float* Q2  = (const float*)d_in[6];  // [16,16]
    const float* Q3  = (const float*)d_in[7];  // [12,12]
    float* out = (float*)d_out;                // [16384,3072]

    char* ws = (char*)d_ws;
    u16*   xb  = (u16*)ws;                                    // 100,663,296 B
    u16*   Ub  = (u16*)(ws + 100663296);                      //  18,874,368 B
    u16*   Vt  = (u16*)(ws + 100663296 + 18874368);           //  18,874,368 B
    float* W   = (float*)(ws + 100663296 + 2 * 18874368);     //  37,748,736 B
    u16*   WtT = Ub;  // alias: Ub is dead once gemm1 completes

    // 1) xb = bf16(x)
    hipLaunchKernelGGL(conv_bf16, dim3(24576), dim3(256), 0, stream, x, xb);
    // 2) Ub = bf16(U * relu(S+delta))
    hipLaunchKernelGGL(conv_scale, dim3(6, 3072), dim3(64), 0, stream, U, S, dl, Ub);
    // 3) Vt = bf16(V^T)
    hipLaunchKernelGGL(transpose_conv, dim3(48, 48), dim3(256), 0, stream, V, Vt, 3072);
    // 4) W = Ub @ Vt^T  (= (U*Sp) @ V)  -- 144 blocks, operands L3-resident
    hipLaunchKernelGGL(gemm256, dim3(12, 12), dim3(512), 0, stream,
                       Ub, Vt, W, 3072, 3072, 3072);
    // 5) WtT[o,:] = bf16(kron(Q1,Q2,Q3) @ W[o,:])
    hipLaunchKernelGGL(kron_apply, dim3(3072), dim3(256), 0, stream, W, Q1, Q2, Q3, WtT);
    // 6) out = xb @ WtT^T  (= x @ W_t)  -- 768 blocks
    hipLaunchKernelGGL(gemm256, dim3(12, 64), dim3(512), 0, stream,
                       xb, WtT, out, 16384, 3072, 3072);
}

// Round 3
// 850.086 us; speedup vs baseline: 1.0271x; 1.0271x over previous
//
#include <hip/hip_runtime.h>

typedef unsigned short u16;
typedef unsigned int u32;
typedef __attribute__((ext_vector_type(8))) __bf16 bf16x8;
typedef __attribute__((ext_vector_type(4))) float f32x4;
typedef __attribute__((ext_vector_type(8))) u16 u16x8;

// ---------- helpers ----------

__device__ __forceinline__ u16 f2bf(float f) {
    union { float f; u32 u; } v; v.f = f;
    u32 r = v.u + 0x7FFFu + ((v.u >> 16) & 1u);   // RNE
    return (u16)(r >> 16);
}

__device__ __forceinline__ void gload16(const void* g, void* l) {
    __builtin_amdgcn_global_load_lds(
        (const __attribute__((address_space(1))) u32*)g,
        (__attribute__((address_space(3))) u32*)l,
        16, 0, 0);
}

// ---------- fp32 -> bf16 elementwise (8 elems/thread) ----------
__global__ __launch_bounds__(256) void conv_bf16(
    const float* __restrict__ in, u16* __restrict__ out) {
    const size_t i = (size_t)blockIdx.x * 256 + threadIdx.x;
    const float4 a = ((const float4*)in)[i * 2];
    const float4 b = ((const float4*)in)[i * 2 + 1];
    u16x8 o;
    o[0] = f2bf(a.x); o[1] = f2bf(a.y); o[2] = f2bf(a.z); o[3] = f2bf(a.w);
    o[4] = f2bf(b.x); o[5] = f2bf(b.y); o[6] = f2bf(b.z); o[7] = f2bf(b.w);
    ((u16x8*)out)[i] = o;
}

// ---------- Ub[m,k] = bf16(U[m,k] * relu(S[k]+delta[k])) ----------
__global__ __launch_bounds__(64) void conv_scale(
    const float* __restrict__ U, const float* __restrict__ S,
    const float* __restrict__ D, u16* __restrict__ out) {
    const int m = blockIdx.y;
    const int k = (blockIdx.x * 64 + threadIdx.x) * 8;
    const size_t base = (size_t)m * 3072 + k;
    const float4 a = *(const float4*)&U[base];
    const float4 b = *(const float4*)&U[base + 4];
    const float4 s1 = *(const float4*)&S[k], s2 = *(const float4*)&S[k + 4];
    const float4 d1 = *(const float4*)&D[k], d2 = *(const float4*)&D[k + 4];
    u16x8 o;
    o[0] = f2bf(a.x * fmaxf(s1.x + d1.x, 0.f));
    o[1] = f2bf(a.y * fmaxf(s1.y + d1.y, 0.f));
    o[2] = f2bf(a.z * fmaxf(s1.z + d1.z, 0.f));
    o[3] = f2bf(a.w * fmaxf(s1.w + d1.w, 0.f));
    o[4] = f2bf(b.x * fmaxf(s2.x + d2.x, 0.f));
    o[5] = f2bf(b.y * fmaxf(s2.y + d2.y, 0.f));
    o[6] = f2bf(b.z * fmaxf(s2.z + d2.z, 0.f));
    o[7] = f2bf(b.w * fmaxf(s2.w + d2.w, 0.f));
    *(u16x8*)&out[base] = o;
}

// ---------- V^T -> bf16 (tiled transpose + convert) ----------
__global__ __launch_bounds__(256) void transpose_conv(
    const float* __restrict__ V, u16* __restrict__ Vt, int n) {
    __shared__ float tile[64][65];
    const int k0 = blockIdx.y * 64, j0 = blockIdx.x * 64;
    const int t = threadIdx.x;
    const int r = t >> 4, c4 = t & 15;
#pragma unroll
    for (int i = 0; i < 4; i++) {
        int row = i * 16 + r;
        const float4 v = *(const float4*)&V[(size_t)(k0 + row) * n + j0 + c4 * 4];
        tile[row][c4 * 4 + 0] = v.x;
        tile[row][c4 * 4 + 1] = v.y;
        tile[row][c4 * 4 + 2] = v.z;
        tile[row][c4 * 4 + 3] = v.w;
    }
    __syncthreads();
#pragma unroll
    for (int i = 0; i < 4; i++) {
        int row = i * 16 + r;  // local j
        ushort4 o;
        o.x = f2bf(tile[c4 * 4 + 0][row]);
        o.y = f2bf(tile[c4 * 4 + 1][row]);
        o.z = f2bf(tile[c4 * 4 + 2][row]);
        o.w = f2bf(tile[c4 * 4 + 3][row]);
        *(ushort4*)&Vt[(size_t)(j0 + row) * n + k0 + c4 * 4] = o;
    }
}

// ---------- bf16 NT GEMM, 256x256 tile, 4-phase/K-tile counted-vmcnt schedule ----------
// 512 threads = 8 waves (2M x 4N); each wave owns 128x64 output (8x4 16x16x32 frags).
// LDS per operand: [2 dbuf][256 rows][64 cols] bf16 (32 KiB tiles, 128 KiB total).
// Bank-conflict-free chunk swizzle (the R0 gemm_bt scheme, measured 0 conflicts):
// global 16B chunk c of row r is stored at LDS slot c ^ (r&7) — applied by
// pre-swizzling the GLOBAL source chunk (global_load_lds dest must stay lane-linear);
// fragment read de-applies it with slot = quad ^ (lrow&7), kk=1 half via XOR 32.
// Lanes then partition into 8-lane groups each covering all 8 chunk groups = all
// 32 banks per cycle (row stride 128 B contributes 0 mod 32 banks).
// Stage granularity: row-quarter (64 rows x 64 cols = 8KB = one gload16 x 512 thr).
// Issue plan per K-tile tt: ph1 -> A q1,q3 (tt+1); ph2 -> B q2,q3 (tt+1);
// ph4 -> A q0,q2 + B q0,q1 (tt+2); one boundary s_waitcnt vmcnt(4) per K-tile
// (never 0 in steady state; the 4 newest loads stay in flight across the barrier).
// Requires M%256==0, N%256==0, K%64==0, K>=128, grid%8==0.
__global__ __launch_bounds__(512, 2) void gemm256(
    const u16* __restrict__ A, const u16* __restrict__ B,
    float* __restrict__ C, int M, int N, int K) {
    __shared__ u16 As[2][16384];
    __shared__ u16 Bs[2][16384];
    const int t = threadIdx.x;

    // XCD-aware swizzle (bijective since grid size % 8 == 0)
    const int nbx = gridDim.x;
    const int bid = blockIdx.y * nbx + blockIdx.x;
    const int cpx = (nbx * gridDim.y) >> 3;
    const int sid = (bid & 7) * cpx + (bid >> 3);
    const int m0 = (sid / nbx) * 256, n0 = (sid % nbx) * 256;

    const int lane = t & 63, quad = lane >> 4, lrow = lane & 15;
    const int wave = t >> 6, wr = wave >> 2, wc = wave & 3;

    // staging: thread t covers row (t>>3); source chunk pre-swizzled by row&7
    const int schunk = (t & 7) ^ ((t >> 3) & 7);
    const u16* Ag = A + (size_t)(m0 + (t >> 3)) * K + schunk * 8;
    const u16* Bg = B + (size_t)(n0 + (t >> 3)) * K + schunk * 8;

    // fragment read offsets (u16 index inside one [256][64] region)
    const int sl = quad ^ (lrow & 7);              // de-swizzled slot for kk=0
    const int aoff = (wr * 128 + lrow) * 64 + sl * 8;
    const int boff = (wc * 64 + lrow) * 64 + sl * 8;

    f32x4 acc[8][4] = {};

    // stage one quarter (q=0..3: rows q*64..q*64+63) of K-tile starting at u16 col kbe
#define STGA(dst, q, kbe) gload16(Ag + (size_t)(q) * 64 * K + (kbe), (char*)(dst) + (q) * 8192 + t * 16)
#define STGB(dst, q, kbe) gload16(Bg + (size_t)(q) * 64 * K + (kbe), (char*)(dst) + (q) * 8192 + t * 16)

    const int NT = K >> 6;
    // prologue: tile0 all 8 quarters; tile1's ph4-equivalent quad
    STGA(As[0], 0, 0); STGA(As[0], 1, 0); STGA(As[0], 2, 0); STGA(As[0], 3, 0);
    STGB(Bs[0], 0, 0); STGB(Bs[0], 1, 0); STGB(Bs[0], 2, 0); STGB(Bs[0], 3, 0);
    if (NT > 1) {
        STGA(As[1], 0, 64); STGA(As[1], 2, 64);
        STGB(Bs[1], 0, 64); STGB(Bs[1], 1, 64);
        asm volatile("s_waitcnt vmcnt(4)" ::: "memory");
    } else {
        asm volatile("s_waitcnt vmcnt(0)" ::: "memory");
    }
    __builtin_amdgcn_s_barrier();

    for (int tt = 0; tt < NT; ++tt) {
        const int b = tt & 1;
        const u16* Acur = As[b];
        const u16* Bcur = Bs[b];
        u16* Anxt = As[b ^ 1];
        u16* Bnxt = Bs[b ^ 1];
        bf16x8 bq[4], aq[4];

#define PHASE_TAIL(OFF)                                                       \
        __builtin_amdgcn_s_barrier();                                         \
        asm volatile("s_waitcnt lgkmcnt(0)" ::: "memory");                    \
        __builtin_amdgcn_sched_barrier(0);                                    \
        __builtin_amdgcn_s_setprio(1);                                        \
        _Pragma("unroll")                                                     \
        for (int mi = 0; mi < 4; mi++)                                        \
            _Pragma("unroll")                                                 \
            for (int ni = 0; ni < 4; ni++)                                    \
                acc[mi + OFF][ni] = __builtin_amdgcn_mfma_f32_16x16x32_bf16(  \
                    aq[mi], bq[ni], acc[mi + OFF][ni], 0, 0, 0);              \
        __builtin_amdgcn_s_setprio(0);

        // ---- phase 1: kk=0, mi 0-3 (8 ds_read) | stage A q1,q3 (tt+1) ----
#pragma unroll
        for (int ni = 0; ni < 4; ni++) bq[ni] = *(const bf16x8*)&Bcur[boff + ni * 1024];
#pragma unroll
        for (int mi = 0; mi < 4; mi++) aq[mi] = *(const bf16x8*)&Acur[aoff + mi * 1024];
        if (tt + 1 < NT) { STGA(Anxt, 1, (tt + 1) * 64); STGA(Anxt, 3, (tt + 1) * 64); }
        PHASE_TAIL(0)
        __builtin_amdgcn_s_barrier();

        // ---- phase 2: kk=0, mi 4-7 (4 ds_read) | stage B q2,q3 (tt+1) ----
#pragma unroll
        for (int mi = 0; mi < 4; mi++) aq[mi] = *(const bf16x8*)&Acur[aoff + (mi + 4) * 1024];
        if (tt + 1 < NT) { STGB(Bnxt, 2, (tt + 1) * 64); STGB(Bnxt, 3, (tt + 1) * 64); }
        PHASE_TAIL(4)
        __builtin_amdgcn_s_barrier();

        // ---- phase 3: kk=1 (slot XOR 32), mi 0-3 (8 ds_read) | no stage ----
#pragma unroll
        for (int ni = 0; ni < 4; ni++) bq[ni] = *(const bf16x8*)&Bcur[(boff + ni * 1024) ^ 32];
#pragma unroll
        for (int mi = 0; mi < 4; mi++) aq[mi] = *(const bf16x8*)&Acur[(aoff + mi * 1024) ^ 32];
        PHASE_TAIL(0)
        __builtin_amdgcn_s_barrier();

        // ---- phase 4: kk=1, mi 4-7 (4 ds_read) | stage A q0,q2 + B q0,q1 (tt+2) ----
#pragma unroll
        for (int mi = 0; mi < 4; mi++) aq[mi] = *(const bf16x8*)&Acur[(aoff + (mi + 4) * 1024) ^ 32];
        if (tt + 2 < NT) {
            STGA((u16*)Acur, 0, (tt + 2) * 64); STGA((u16*)Acur, 2, (tt + 2) * 64);
            STGB((u16*)Bcur, 0, (tt + 2) * 64); STGB((u16*)Bcur, 1, (tt + 2) * 64);
        }
        PHASE_TAIL(4)
        if (tt + 2 < NT)
            asm volatile("s_waitcnt vmcnt(4)" ::: "memory");  // tt+1 fully landed; 4 newest stay in flight
        else
            asm volatile("s_waitcnt vmcnt(0)" ::: "memory");  // tail drain
        __builtin_amdgcn_s_barrier();
#undef PHASE_TAIL
    }
#undef STGA
#undef STGB

    // epilogue: C/D layout col=lane&15, row=quad*4+reg
#pragma unroll
    for (int mi = 0; mi < 8; mi++) {
#pragma unroll
        for (int rr = 0; rr < 4; rr++) {
            const int row = m0 + wr * 128 + mi * 16 + quad * 4 + rr;
            float* cp = C + (size_t)row * N + n0 + wc * 64 + lrow;
#pragma unroll
            for (int ni = 0; ni < 4; ni++) cp[ni * 16] = acc[mi][ni][rr];
        }
    }
}

// ---------- Kron apply: WtT[o,:] = bf16( (Q1 (x) Q2 (x) Q3) @ W[o,:] ) ----------
__global__ __launch_bounds__(256) void kron_apply(
    const float* __restrict__ W, const float* __restrict__ Q1,
    const float* __restrict__ Q2, const float* __restrict__ Q3,
    u16* __restrict__ WtT) {
    __shared__ float T0[3072], T1[3072];
    __shared__ float Q1s[256], Q2s[256], Q3s[144];
    const int o = blockIdx.x, t = threadIdx.x;
#pragma unroll
    for (int i = 0; i < 12; i++) T0[t + i * 256] = W[(size_t)o * 3072 + t + i * 256];
    Q1s[t] = Q1[t];
    Q2s[t] = Q2[t];
    if (t < 144) Q3s[t] = Q3[t];
    __syncthreads();
#pragma unroll
    for (int i = 0; i < 12; i++) {
        int e = t + i * 256;
        int d1 = e / 192, rem = e % 192;
        float s = 0.f;
#pragma unroll
        for (int j1 = 0; j1 < 16; j1++) s += Q1s[d1 * 16 + j1] * T0[j1 * 192 + rem];
        T1[e] = s;
    }
    __syncthreads();
#pragma unroll
    for (int i = 0; i < 12; i++) {
        int e = t + i * 256;
        int j3 = e % 12, d2 = (e / 12) & 15, d1 = e / 192;
        float s = 0.f;
#pragma unroll
        for (int j2 = 0; j2 < 16; j2++) s += Q2s[d2 * 16 + j2] * T1[d1 * 192 + j2 * 12 + j3];
        T0[e] = s;
    }
    __syncthreads();
#pragma unroll
    for (int i = 0; i < 12; i++) {
        int e = t + i * 256;
        int d3 = e % 12, b = e - d3;
        float s = 0.f;
#pragma unroll
        for (int j3 = 0; j3 < 12; j3++) s += Q3s[d3 * 12 + j3] * T0[b + j3];
        WtT[(size_t)o * 3072 + e] = f2bf(s);
    }
}

// ---------- launch ----------
extern "C" void kernel_launch(void* const* d_in, const int* in_sizes, int n_in,
                              void* d_out, int out_size, void* d_ws, size_t ws_size,
                              hipStream_t stream) {
    const float* x   = (const float*)d_in[0];  // [4,4096,3072]
    const float* U   = (const float*)d_in[1];  // [3072,3072]
    const float* S   = (const float*)d_in[2];  // [3072]
    const float* V   = (const float*)d_in[3];  // [3072,3072]
    const float* dl  = (const float*)d_in[4];  // [3072]
    const float* Q1  = (const float*)d_in[5];  // [16,16]
    const float* Q2  = (const float*)d_in[6];  // [16,16]
    const float* Q3  = (const float*)d_in[7];  // [12,12]
    float* out = (float*)d_out;                // [16384,3072]

    char* ws = (char*)d_ws;
    u16*   xb  = (u16*)ws;                                    // 100,663,296 B
    u16*   Ub  = (u16*)(ws + 100663296);                      //  18,874,368 B
    u16*   Vt  = (u16*)(ws + 100663296 + 18874368);           //  18,874,368 B
    float* W   = (float*)(ws + 100663296 + 2 * 18874368);     //  37,748,736 B
    u16*   WtT = Ub;  // alias: Ub is dead once gemm1 completes

    // 1) xb = bf16(x)
    hipLaunchKernelGGL(conv_bf16, dim3(24576), dim3(256), 0, stream, x, xb);
    // 2) Ub = bf16(U * relu(S+delta))
    hipLaunchKernelGGL(conv_scale, dim3(6, 3072), dim3(64), 0, stream, U, S, dl, Ub);
    // 3) Vt = bf16(V^T)
    hipLaunchKernelGGL(transpose_conv, dim3(48, 48), dim3(256), 0, stream, V, Vt, 3072);
    // 4) W = Ub @ Vt^T  (= (U*Sp) @ V)  -- 144 blocks, operands L3-resident
    hipLaunchKernelGGL(gemm256, dim3(12, 12), dim3(512), 0, stream,
                       Ub, Vt, W, 3072, 3072, 3072);
    // 5) WtT[o,:] = bf16(kron(Q1,Q2,Q3) @ W[o,:])
    hipLaunchKernelGGL(kron_apply, dim3(3072), dim3(256), 0, stream, W, Q1, Q2, Q3, WtT);
    // 6) out = xb @ WtT^T  (= x @ W_t)  -- 768 blocks
    hipLaunchKernelGGL(gemm256, dim3(12, 64), dim3(512), 0, stream,
                       xb, WtT, out, 16384, 3072, 3072);
}